// Round 2
// 403.660 us; speedup vs baseline: 1.0594x; 1.0594x over previous
//
#include <hip/hip_runtime.h>
#include <hip/hip_bf16.h>

static constexpr int cB  = 16;
static constexpr int cS  = 512;
static constexpr int cD  = 256;
static constexpr int cH  = 8;
static constexpr int cDH = 32;

typedef __attribute__((ext_vector_type(8))) short short8v;
typedef __attribute__((ext_vector_type(4))) short short4v;
typedef __attribute__((ext_vector_type(4))) float f32x4;

__device__ __forceinline__ short bfbits(float x) {
    __hip_bfloat16 h = __float2bfloat16(x);
    short s; __builtin_memcpy(&s, &h, 2); return s;
}
__device__ __forceinline__ float bff(short s) {
    __hip_bfloat16 h; __builtin_memcpy(&h, &s, 2); return __bfloat162float(h);
}

// ---------------------------------------------------------------------------
// Projection v2: C = X @ W^T + b via bf16 hi/lo MFMA (f32-grade accuracy).
// grid (8192/32, 3), block 256 (4 waves). No LDS. W fragments come from L2.
// Output stored as (B,H,S,DH) into ws.
// ---------------------------------------------------------------------------
__global__ __launch_bounds__(256) void proj_kernel(
    const float* __restrict__ q_in, const float* __restrict__ k_in,
    const float* __restrict__ v_in,
    const float* __restrict__ Wq, const float* __restrict__ bq,
    const float* __restrict__ Wk, const float* __restrict__ bk,
    const float* __restrict__ Wv, const float* __restrict__ bv,
    float* __restrict__ ws)
{
    const int z = blockIdx.y;
    const float* X    = (z == 0) ? q_in : (z == 1) ? k_in : v_in;
    const float* W    = (z == 0) ? Wq   : (z == 1) ? Wk   : Wv;
    const float* bias = (z == 0) ? bq   : (z == 1) ? bk   : bv;
    float* O = ws + (size_t)z * (cB * cS * cD);

    const int tid  = threadIdx.x;
    const int w    = tid >> 6;
    const int lane = tid & 63;
    const int n16  = lane & 15;
    const int quad = lane >> 4;

    const int i0 = blockIdx.x * 32 + 16 * (w & 1);   // wave's 16-row group
    const int j0 = 128 * (w >> 1);                   // wave's 128-col half

    // ---- A fragments: X rows, full K=256, bf16 hi/lo ----
    const float* xrow = X + (size_t)(i0 + n16) * cD + quad * 8;
    short8v a_hi[8], a_lo[8];
#pragma unroll
    for (int c = 0; c < 8; c++) {
        float xa[8];
        *(float4*)&xa[0] = *(const float4*)(xrow + c * 32);
        *(float4*)&xa[4] = *(const float4*)(xrow + c * 32 + 4);
#pragma unroll
        for (int j = 0; j < 8; j++) {
            short hb = bfbits(xa[j]);
            a_hi[c][j] = hb;
            a_lo[c][j] = bfbits(xa[j] - bff(hb));
        }
    }

    // ---- 8 col tiles of 16x16, K-chunks of 32 ----
#pragma unroll
    for (int t = 0; t < 8; t++) {
        const int jb = j0 + t * 16;
        const float* wrow = W + (size_t)(jb + n16) * cD + quad * 8;
        f32x4 acc = (f32x4){0.f, 0.f, 0.f, 0.f};
#pragma unroll
        for (int c = 0; c < 8; c++) {
            float wv_[8];
            *(float4*)&wv_[0] = *(const float4*)(wrow + c * 32);
            *(float4*)&wv_[4] = *(const float4*)(wrow + c * 32 + 4);
            short8v b_hi, b_lo;
#pragma unroll
            for (int j = 0; j < 8; j++) {
                short hb = bfbits(wv_[j]);
                b_hi[j] = hb;
                b_lo[j] = bfbits(wv_[j] - bff(hb));
            }
            acc = __builtin_amdgcn_mfma_f32_16x16x32_bf16(a_hi[c], b_hi, acc, 0, 0, 0);
            acc = __builtin_amdgcn_mfma_f32_16x16x32_bf16(a_hi[c], b_lo, acc, 0, 0, 0);
            acc = __builtin_amdgcn_mfma_f32_16x16x32_bf16(a_lo[c], b_hi, acc, 0, 0, 0);
        }
        // D: row = i0 + quad*4 + r, col = jb + n16
        const int jg = jb + n16;
        const float bv_ = bias[jg];
        const int h_ = jg >> 5, dh = jg & 31;
#pragma unroll
        for (int r = 0; r < 4; r++) {
            int gi = i0 + quad * 4 + r;
            int b_ = gi >> 9, s_ = gi & 511;
            O[(((size_t)(b_ * cH + h_)) * cS + s_) * cDH + dh] = acc[r] + bv_;
        }
    }
}

// ---------------------------------------------------------------------------
// Ev kernel: Ev[b][q][k] = Bc*time_attn + Cc*rel_attn  (head-independent),
// stored bf16. One wave per (b,q) row.
// ---------------------------------------------------------------------------
__global__ __launch_bounds__(256) void ev_kernel(
    const float* __restrict__ rel, const float* __restrict__ ts,
    const float* __restrict__ l1p, const float* __restrict__ l2p,
    short* __restrict__ Evb)
{
    const int w = threadIdx.x >> 6, lane = threadIdx.x & 63;
    const int row = blockIdx.x * 4 + w;          // b*512 + q
    const int q = row & 511;
    const float* tr = ts  + (size_t)row * cS;
    const float* rr = rel + (size_t)row * cS;
    const float l1 = l1p[0], l2 = l2p[0];
    const float Bc = (1.f - l1) * l2;
    const float Cc = l1;

    float tv[8], rv[8];
    float tmax = -1e30f, rmax = -1e30f;
#pragma unroll
    for (int j = 0; j < 8; j++) {
        int k = lane + 64 * j;
        float t = __expf(-fabsf(tr[k]));
        float r = rr[k];
        r = (k > q && r != 0.f) ? r : -10000.f;
        tv[j] = (k <= q) ? t : -1e30f;
        rv[j] = r;
        tmax = fmaxf(tmax, tv[j]);
        rmax = fmaxf(rmax, r);
    }
#pragma unroll
    for (int m = 1; m < 64; m <<= 1) {
        tmax = fmaxf(tmax, __shfl_xor(tmax, m, 64));
        rmax = fmaxf(rmax, __shfl_xor(rmax, m, 64));
    }
    float te[8], re[8];
    float tsum = 0.f, rsum = 0.f;
#pragma unroll
    for (int j = 0; j < 8; j++) {
        te[j] = (tv[j] > -1e29f) ? __expf(tv[j] - tmax) : 0.f;
        re[j] = __expf(rv[j] - rmax);
        tsum += te[j]; rsum += re[j];
    }
#pragma unroll
    for (int m = 1; m < 64; m <<= 1) {
        tsum += __shfl_xor(tsum, m, 64);
        rsum += __shfl_xor(rsum, m, 64);
    }
    const float ti = Bc / tsum, ri = Cc / rsum;
#pragma unroll
    for (int j = 0; j < 8; j++) {
        int k = lane + 64 * j;
        Evb[(size_t)row * cS + k] = bfbits(te[j] * ti + re[j] * ri);
    }
}

// ---------------------------------------------------------------------------
// Attention v3: XCD-aware block remap (all blocks of one batch share an XCD
// so K/V/Ev L2-hit), contiguous-per-instruction nontemporal prob stores.
// One block per (b,h,32-q-tile). MFMA QK^T (bf16 hi/lo split), in-register
// softmax, P through LDS bf16, MFMA PV.
// ---------------------------------------------------------------------------
__global__ __launch_bounds__(256) void attn2_kernel(
    const float* __restrict__ ws, const short* __restrict__ Evb,
    const float* __restrict__ l1p, const float* __restrict__ l2p,
    float* __restrict__ out, float* __restrict__ prob)
{
    constexpr int PS = 536;                       // P row stride (bf16 elems)
    __shared__ short Pl[32 * PS];                 // 33.5 KB
    __shared__ float redM[2][32];
    __shared__ float redS[2][32];

    const int tid  = threadIdx.x;
    const int w    = tid >> 6;
    const int lane = tid & 63;
    const int n16  = lane & 15;
    const int quad = lane >> 4;

    // ---- XCD-aware remap: hardware assigns XCD = flat_id % 8 (round-robin).
    // Make all 128 blocks of batch b run on XCD b%8 so K/V (1 MB/batch) and
    // Ev (0.5 MB/batch) are fetched from HBM once and L2-hit thereafter.
    const int flat = blockIdx.y * gridDim.x + blockIdx.x;   // 0..2047
    const int xcd  = flat & 7;
    const int slot = flat >> 3;                   // 0..255
    const int b  = xcd + 8 * (slot >> 7);         // 0..15
    const int h  = (slot >> 4) & 7;               // 0..7
    const int qt = slot & 15;                     // 0..15
    const size_t bh = (size_t)b * cH + h;
    const int q0 = qt * 32;

    const float* qh = ws;
    const float* kh = ws + (size_t)cB * cS * cD;
    const float* vh = ws + 2 * (size_t)cB * cS * cD;

    const float l1 = l1p[0], l2 = l2p[0];
    const float Ac = (1.f - l1) * (1.f - l2);

    const int qhH = w & 1;                        // which 16 q rows
    const int kh2 = w >> 1;                       // which 256 keys
    const int kbase = 256 * kh2;

    // ---- A fragment: Q rows (hi/lo bf16 split) ----
    const int rowA = q0 + 16 * qhH + n16;
    const float* qrow = qh + (bh * cS + rowA) * cDH + quad * 8;
    float qa[8];
    *(float4*)&qa[0] = *(const float4*)qrow;
    *(float4*)&qa[4] = *(const float4*)(qrow + 4);
    short8v a_hi, a_lo;
#pragma unroll
    for (int j = 0; j < 8; j++) {
        short hbits = bfbits(qa[j]);
        a_hi[j] = hbits;
        a_lo[j] = bfbits(qa[j] - bff(hbits));
    }

    // ---- QK^T MFMA over this wave's 16 key tiles ----
    f32x4 acc[16];
#pragma unroll
    for (int t = 0; t < 16; t++) acc[t] = (f32x4){0.f, 0.f, 0.f, 0.f};

    const int tl = (kbase <= q0 + 31) ? min(15, (q0 + 31 - kbase) >> 4) : -1;
    for (int t = 0; t <= tl; t++) {
        const float* krow = kh + (bh * cS + kbase + 16 * t + n16) * cDH + quad * 8;
        float kb[8];
        *(float4*)&kb[0] = *(const float4*)krow;
        *(float4*)&kb[4] = *(const float4*)(krow + 4);
        short8v b_hi, b_lo;
#pragma unroll
        for (int j = 0; j < 8; j++) {
            short hbits = bfbits(kb[j]);
            b_hi[j] = hbits;
            b_lo[j] = bfbits(kb[j] - bff(hbits));
        }
        acc[t] = __builtin_amdgcn_mfma_f32_16x16x32_bf16(a_hi, b_hi, acc[t], 0, 0, 0);
        acc[t] = __builtin_amdgcn_mfma_f32_16x16x32_bf16(a_hi, b_lo, acc[t], 0, 0, 0);
        acc[t] = __builtin_amdgcn_mfma_f32_16x16x32_bf16(a_lo, b_hi, acc[t], 0, 0, 0);
    }

    // ---- mask + scale + row max (rows rowD = q0+16*qhH+quad*4+r) ----
    const float scale = 0.17677669529663687f;
    const int rowDl = 16 * qhH + quad * 4;        // local row base (0..28)
    float Mx0 = -1e30f, Mx1 = -1e30f, Mx2 = -1e30f, Mx3 = -1e30f;
#pragma unroll
    for (int t = 0; t < 16; t++) {
        const int kg = kbase + 16 * t + n16;
        const int rg = q0 + rowDl;
        float s0 = (kg <= rg + 0) ? acc[t][0] * scale : -1e30f;
        float s1 = (kg <= rg + 1) ? acc[t][1] * scale : -1e30f;
        float s2 = (kg <= rg + 2) ? acc[t][2] * scale : -1e30f;
        float s3 = (kg <= rg + 3) ? acc[t][3] * scale : -1e30f;
        acc[t][0] = s0; acc[t][1] = s1; acc[t][2] = s2; acc[t][3] = s3;
        Mx0 = fmaxf(Mx0, s0); Mx1 = fmaxf(Mx1, s1);
        Mx2 = fmaxf(Mx2, s2); Mx3 = fmaxf(Mx3, s3);
    }
#pragma unroll
    for (int m = 1; m < 16; m <<= 1) {
        Mx0 = fmaxf(Mx0, __shfl_xor(Mx0, m, 64));
        Mx1 = fmaxf(Mx1, __shfl_xor(Mx1, m, 64));
        Mx2 = fmaxf(Mx2, __shfl_xor(Mx2, m, 64));
        Mx3 = fmaxf(Mx3, __shfl_xor(Mx3, m, 64));
    }
    if (n16 == 0) {
        redM[kh2][rowDl + 0] = Mx0; redM[kh2][rowDl + 1] = Mx1;
        redM[kh2][rowDl + 2] = Mx2; redM[kh2][rowDl + 3] = Mx3;
    }
    __syncthreads();
    float Mg0 = fmaxf(redM[0][rowDl + 0], redM[1][rowDl + 0]);
    float Mg1 = fmaxf(redM[0][rowDl + 1], redM[1][rowDl + 1]);
    float Mg2 = fmaxf(redM[0][rowDl + 2], redM[1][rowDl + 2]);
    float Mg3 = fmaxf(redM[0][rowDl + 3], redM[1][rowDl + 3]);

    // ---- exp + row sum ----
    float S0 = 0.f, S1 = 0.f, S2 = 0.f, S3 = 0.f;
#pragma unroll
    for (int t = 0; t < 16; t++) {
        float e0 = __expf(acc[t][0] - Mg0);
        float e1 = __expf(acc[t][1] - Mg1);
        float e2 = __expf(acc[t][2] - Mg2);
        float e3 = __expf(acc[t][3] - Mg3);
        acc[t][0] = e0; acc[t][1] = e1; acc[t][2] = e2; acc[t][3] = e3;
        S0 += e0; S1 += e1; S2 += e2; S3 += e3;
    }
#pragma unroll
    for (int m = 1; m < 16; m <<= 1) {
        S0 += __shfl_xor(S0, m, 64); S1 += __shfl_xor(S1, m, 64);
        S2 += __shfl_xor(S2, m, 64); S3 += __shfl_xor(S3, m, 64);
    }
    if (n16 == 0) {
        redS[kh2][rowDl + 0] = S0; redS[kh2][rowDl + 1] = S1;
        redS[kh2][rowDl + 2] = S2; redS[kh2][rowDl + 3] = S3;
    }
    __syncthreads();
    const float i0 = Ac / (redS[0][rowDl + 0] + redS[1][rowDl + 0]);
    const float i1 = Ac / (redS[0][rowDl + 1] + redS[1][rowDl + 1]);
    const float i2 = Ac / (redS[0][rowDl + 2] + redS[1][rowDl + 2]);
    const float i3 = Ac / (redS[0][rowDl + 3] + redS[1][rowDl + 3]);

    // ---- store softmax part to P (bf16) ----
#pragma unroll
    for (int t = 0; t < 16; t++) {
        const int col = kbase + 16 * t + n16;
        Pl[(rowDl + 0) * PS + col] = bfbits(acc[t][0] * i0);
        Pl[(rowDl + 1) * PS + col] = bfbits(acc[t][1] * i1);
        Pl[(rowDl + 2) * PS + col] = bfbits(acc[t][2] * i2);
        Pl[(rowDl + 3) * PS + col] = bfbits(acc[t][3] * i3);
    }
    __syncthreads();

    // ---- blend with Ev + contiguous nontemporal prob write + P write-back.
    // One f32x4 per lane: each store instruction covers a contiguous 1 KB
    // across the wave (was 16B-at-32B-stride before -> write amplification).
#pragma unroll
    for (int it = 0; it < 16; it++) {
        const int idx = it * 256 + tid;           // 0..4095
        const int r = idx >> 7;                   // 0..31
        const int c0 = (idx & 127) * 4;           // 0..508
        short* pp = &Pl[r * PS + c0];
        short4v pv = *(short4v*)pp;
        const short4v ev = *(const short4v*)(Evb + ((size_t)(b * cS + q0 + r)) * cS + c0);
        f32x4 o;
#pragma unroll
        for (int j = 0; j < 4; j++) o[j] = bff(pv[j]) + bff(ev[j]);
        __builtin_nontemporal_store(o, (f32x4*)(prob + (bh * cS + q0 + r) * cS + c0));
#pragma unroll
        for (int j = 0; j < 4; j++) pv[j] = bfbits(o[j]);
        *(short4v*)pp = pv;
    }
    __syncthreads();

    // ---- PV: out^T(32x32) = V^T(32x512) @ P^T(512x32), 1 tile per wave ----
    const int dhT = w & 1, qT = w >> 1;
    const int dhA = 16 * dhT + n16;
    f32x4 oacc = (f32x4){0.f, 0.f, 0.f, 0.f};
    for (int k0 = 0; k0 < cS; k0 += 32) {
        const float* vp = vh + (bh * cS + k0 + quad * 8) * cDH + dhA;
        short8v av;
#pragma unroll
        for (int j = 0; j < 8; j++) av[j] = bfbits(vp[j * cDH]);
        short8v bv = *(short8v*)&Pl[(16 * qT + n16) * PS + k0 + quad * 8];
        oacc = __builtin_amdgcn_mfma_f32_16x16x32_bf16(av, bv, oacc, 0, 0, 0);
    }
    const int qg = q0 + 16 * qT + n16;
    const int dhD = 16 * dhT + quad * 4;
    float* op = out + ((size_t)b * cS + qg) * cD + h * cDH + dhD;
    __builtin_nontemporal_store(oacc, (f32x4*)op);
}

extern "C" void kernel_launch(void* const* d_in, const int* in_sizes, int n_in,
                              void* d_out, int out_size, void* d_ws, size_t ws_size,
                              hipStream_t stream) {
    const float* query = (const float*)d_in[0];
    const float* key   = (const float*)d_in[1];
    const float* value = (const float*)d_in[2];
    const float* rel   = (const float*)d_in[3];
    const float* tsp   = (const float*)d_in[4];
    const float* l1 = (const float*)d_in[6];
    const float* l2 = (const float*)d_in[7];
    const float* Wq = (const float*)d_in[8];
    const float* bq = (const float*)d_in[9];
    const float* Wk = (const float*)d_in[10];
    const float* bk = (const float*)d_in[11];
    const float* Wv = (const float*)d_in[12];
    const float* bv = (const float*)d_in[13];

    float* ws   = (float*)d_ws;
    short* Evb  = (short*)(ws + 3 * (size_t)cB * cS * cD);   // bf16, 8.4 MB
    float* out  = (float*)d_out;
    float* prob = out + (size_t)cB * cS * cD;

    proj_kernel<<<dim3(256, 3), 256, 0, stream>>>(query, key, value,
                                                  Wq, bq, Wk, bk, Wv, bv, ws);
    ev_kernel<<<dim3(2048), 256, 0, stream>>>(rel, tsp, l1, l2, Evb);
    attn2_kernel<<<dim3(16, 128), 256, 0, stream>>>(ws, Evb, l1, l2, out, prob);
}

// Round 3
// 402.292 us; speedup vs baseline: 1.0630x; 1.0034x over previous
//
#include <hip/hip_runtime.h>
#include <hip/hip_bf16.h>

static constexpr int cB  = 16;
static constexpr int cS  = 512;
static constexpr int cD  = 256;
static constexpr int cH  = 8;
static constexpr int cDH = 32;

typedef __attribute__((ext_vector_type(8))) short short8v;
typedef __attribute__((ext_vector_type(4))) short short4v;
typedef __attribute__((ext_vector_type(4))) float f32x4;

__device__ __forceinline__ short bfbits(float x) {
    __hip_bfloat16 h = __float2bfloat16(x);
    short s; __builtin_memcpy(&s, &h, 2); return s;
}
__device__ __forceinline__ float bff(short s) {
    __hip_bfloat16 h; __builtin_memcpy(&h, &s, 2); return __bfloat162float(h);
}

// ---------------------------------------------------------------------------
// Projection v2: C = X @ W^T + b via bf16 hi/lo MFMA (f32-grade accuracy).
// grid (8192/32, 3), block 256 (4 waves). No LDS. W fragments come from L2.
// Output stored as (B,H,S,DH) into ws.
// ---------------------------------------------------------------------------
__global__ __launch_bounds__(256) void proj_kernel(
    const float* __restrict__ q_in, const float* __restrict__ k_in,
    const float* __restrict__ v_in,
    const float* __restrict__ Wq, const float* __restrict__ bq,
    const float* __restrict__ Wk, const float* __restrict__ bk,
    const float* __restrict__ Wv, const float* __restrict__ bv,
    float* __restrict__ ws)
{
    const int z = blockIdx.y;
    const float* X    = (z == 0) ? q_in : (z == 1) ? k_in : v_in;
    const float* W    = (z == 0) ? Wq   : (z == 1) ? Wk   : Wv;
    const float* bias = (z == 0) ? bq   : (z == 1) ? bk   : bv;
    float* O = ws + (size_t)z * (cB * cS * cD);

    const int tid  = threadIdx.x;
    const int w    = tid >> 6;
    const int lane = tid & 63;
    const int n16  = lane & 15;
    const int quad = lane >> 4;

    const int i0 = blockIdx.x * 32 + 16 * (w & 1);   // wave's 16-row group
    const int j0 = 128 * (w >> 1);                   // wave's 128-col half

    // ---- A fragments: X rows, full K=256, bf16 hi/lo ----
    const float* xrow = X + (size_t)(i0 + n16) * cD + quad * 8;
    short8v a_hi[8], a_lo[8];
#pragma unroll
    for (int c = 0; c < 8; c++) {
        float xa[8];
        *(float4*)&xa[0] = *(const float4*)(xrow + c * 32);
        *(float4*)&xa[4] = *(const float4*)(xrow + c * 32 + 4);
#pragma unroll
        for (int j = 0; j < 8; j++) {
            short hb = bfbits(xa[j]);
            a_hi[c][j] = hb;
            a_lo[c][j] = bfbits(xa[j] - bff(hb));
        }
    }

    // ---- 8 col tiles of 16x16, K-chunks of 32 ----
#pragma unroll
    for (int t = 0; t < 8; t++) {
        const int jb = j0 + t * 16;
        const float* wrow = W + (size_t)(jb + n16) * cD + quad * 8;
        f32x4 acc = (f32x4){0.f, 0.f, 0.f, 0.f};
#pragma unroll
        for (int c = 0; c < 8; c++) {
            float wv_[8];
            *(float4*)&wv_[0] = *(const float4*)(wrow + c * 32);
            *(float4*)&wv_[4] = *(const float4*)(wrow + c * 32 + 4);
            short8v b_hi, b_lo;
#pragma unroll
            for (int j = 0; j < 8; j++) {
                short hb = bfbits(wv_[j]);
                b_hi[j] = hb;
                b_lo[j] = bfbits(wv_[j] - bff(hb));
            }
            acc = __builtin_amdgcn_mfma_f32_16x16x32_bf16(a_hi[c], b_hi, acc, 0, 0, 0);
            acc = __builtin_amdgcn_mfma_f32_16x16x32_bf16(a_hi[c], b_lo, acc, 0, 0, 0);
            acc = __builtin_amdgcn_mfma_f32_16x16x32_bf16(a_lo[c], b_hi, acc, 0, 0, 0);
        }
        // D: row = i0 + quad*4 + r, col = jb + n16
        const int jg = jb + n16;
        const float bv_ = bias[jg];
        const int h_ = jg >> 5, dh = jg & 31;
#pragma unroll
        for (int r = 0; r < 4; r++) {
            int gi = i0 + quad * 4 + r;
            int b_ = gi >> 9, s_ = gi & 511;
            O[(((size_t)(b_ * cH + h_)) * cS + s_) * cDH + dh] = acc[r] + bv_;
        }
    }
}

// ---------------------------------------------------------------------------
// Ev kernel v2: Ev[b][q][k] = Bc*time_attn + Cc*rel_attn  (head-independent),
// stored bf16. One wave per (b,q) row. Triangular predicated loads:
// ts only needed for k<=q (else masked -inf), rel only for k>q (else
// relf==0 -> -10000). Halves the 268 MB streaming read to ~140 MB.
// ---------------------------------------------------------------------------
__global__ __launch_bounds__(256) void ev_kernel(
    const float* __restrict__ rel, const float* __restrict__ ts,
    const float* __restrict__ l1p, const float* __restrict__ l2p,
    short* __restrict__ Evb)
{
    const int w = threadIdx.x >> 6, lane = threadIdx.x & 63;
    const int row = blockIdx.x * 4 + w;          // b*512 + q
    const int q = row & 511;
    const float* tr = ts  + (size_t)row * cS;
    const float* rr = rel + (size_t)row * cS;
    const float l1 = l1p[0], l2 = l2p[0];
    const float Bc = (1.f - l1) * l2;
    const float Cc = l1;

    float tv[8], rv[8];
    float tmax = -1e30f, rmax = -1e30f;
#pragma unroll
    for (int j = 0; j < 8; j++) {
        int k = lane + 64 * j;
        // ts used only where k <= q; rel used only where k > q.
        float tl_ = (k <= q) ? tr[k] : 0.f;
        float r   = (k >  q) ? rr[k] : 0.f;
        tv[j] = (k <= q) ? __expf(-fabsf(tl_)) : -1e30f;
        rv[j] = (k > q && r != 0.f) ? r : -10000.f;
        tmax = fmaxf(tmax, tv[j]);
        rmax = fmaxf(rmax, rv[j]);
    }
#pragma unroll
    for (int m = 1; m < 64; m <<= 1) {
        tmax = fmaxf(tmax, __shfl_xor(tmax, m, 64));
        rmax = fmaxf(rmax, __shfl_xor(rmax, m, 64));
    }
    float te[8], re[8];
    float tsum = 0.f, rsum = 0.f;
#pragma unroll
    for (int j = 0; j < 8; j++) {
        te[j] = (tv[j] > -1e29f) ? __expf(tv[j] - tmax) : 0.f;
        re[j] = __expf(rv[j] - rmax);
        tsum += te[j]; rsum += re[j];
    }
#pragma unroll
    for (int m = 1; m < 64; m <<= 1) {
        tsum += __shfl_xor(tsum, m, 64);
        rsum += __shfl_xor(rsum, m, 64);
    }
    const float ti = Bc / tsum, ri = Cc / rsum;
#pragma unroll
    for (int j = 0; j < 8; j++) {
        int k = lane + 64 * j;
        Evb[(size_t)row * cS + k] = bfbits(te[j] * ti + re[j] * ri);
    }
}

// ---------------------------------------------------------------------------
// Attention v4: XCD-aware block remap + __launch_bounds__(256,4).
// LDS caps residency at 4 blocks/CU (= 4 waves/SIMD), so ask for exactly
// that: VGPR cap rises 52 -> 128, letting the compiler software-pipeline
// the L2-hit K/V/Ev loads instead of stalling (VALUBusy was 12%,
// MfmaUtil 1.3% -> kernel was ~90% latency-stalled).
// ---------------------------------------------------------------------------
__global__ __launch_bounds__(256, 4) void attn2_kernel(
    const float* __restrict__ ws, const short* __restrict__ Evb,
    const float* __restrict__ l1p, const float* __restrict__ l2p,
    float* __restrict__ out, float* __restrict__ prob)
{
    constexpr int PS = 536;                       // P row stride (bf16 elems)
    __shared__ short Pl[32 * PS];                 // 33.5 KB
    __shared__ float redM[2][32];
    __shared__ float redS[2][32];

    const int tid  = threadIdx.x;
    const int w    = tid >> 6;
    const int lane = tid & 63;
    const int n16  = lane & 15;
    const int quad = lane >> 4;

    // ---- XCD-aware remap: hardware assigns XCD = flat_id % 8 (round-robin).
    // Make all 128 blocks of batch b run on XCD b%8 so K/V (1 MB/batch) and
    // Ev (0.5 MB/batch) are fetched from HBM once and L2-hit thereafter.
    const int flat = blockIdx.y * gridDim.x + blockIdx.x;   // 0..2047
    const int xcd  = flat & 7;
    const int slot = flat >> 3;                   // 0..255
    const int b  = xcd + 8 * (slot >> 7);         // 0..15
    const int h  = (slot >> 4) & 7;               // 0..7
    const int qt = slot & 15;                     // 0..15
    const size_t bh = (size_t)b * cH + h;
    const int q0 = qt * 32;

    const float* qh = ws;
    const float* kh = ws + (size_t)cB * cS * cD;
    const float* vh = ws + 2 * (size_t)cB * cS * cD;

    const float l1 = l1p[0], l2 = l2p[0];
    const float Ac = (1.f - l1) * (1.f - l2);

    const int qhH = w & 1;                        // which 16 q rows
    const int kh2 = w >> 1;                       // which 256 keys
    const int kbase = 256 * kh2;

    // ---- A fragment: Q rows (hi/lo bf16 split) ----
    const int rowA = q0 + 16 * qhH + n16;
    const float* qrow = qh + (bh * cS + rowA) * cDH + quad * 8;
    float qa[8];
    *(float4*)&qa[0] = *(const float4*)qrow;
    *(float4*)&qa[4] = *(const float4*)(qrow + 4);
    short8v a_hi, a_lo;
#pragma unroll
    for (int j = 0; j < 8; j++) {
        short hbits = bfbits(qa[j]);
        a_hi[j] = hbits;
        a_lo[j] = bfbits(qa[j] - bff(hbits));
    }

    // ---- QK^T MFMA over this wave's 16 key tiles ----
    f32x4 acc[16];
#pragma unroll
    for (int t = 0; t < 16; t++) acc[t] = (f32x4){0.f, 0.f, 0.f, 0.f};

    const int tl = (kbase <= q0 + 31) ? min(15, (q0 + 31 - kbase) >> 4) : -1;
    for (int t = 0; t <= tl; t++) {
        const float* krow = kh + (bh * cS + kbase + 16 * t + n16) * cDH + quad * 8;
        float kb[8];
        *(float4*)&kb[0] = *(const float4*)krow;
        *(float4*)&kb[4] = *(const float4*)(krow + 4);
        short8v b_hi, b_lo;
#pragma unroll
        for (int j = 0; j < 8; j++) {
            short hbits = bfbits(kb[j]);
            b_hi[j] = hbits;
            b_lo[j] = bfbits(kb[j] - bff(hbits));
        }
        acc[t] = __builtin_amdgcn_mfma_f32_16x16x32_bf16(a_hi, b_hi, acc[t], 0, 0, 0);
        acc[t] = __builtin_amdgcn_mfma_f32_16x16x32_bf16(a_hi, b_lo, acc[t], 0, 0, 0);
        acc[t] = __builtin_amdgcn_mfma_f32_16x16x32_bf16(a_lo, b_hi, acc[t], 0, 0, 0);
    }

    // ---- mask + scale + row max (rows rowD = q0+16*qhH+quad*4+r) ----
    const float scale = 0.17677669529663687f;
    const int rowDl = 16 * qhH + quad * 4;        // local row base (0..28)
    float Mx0 = -1e30f, Mx1 = -1e30f, Mx2 = -1e30f, Mx3 = -1e30f;
#pragma unroll
    for (int t = 0; t < 16; t++) {
        const int kg = kbase + 16 * t + n16;
        const int rg = q0 + rowDl;
        float s0 = (kg <= rg + 0) ? acc[t][0] * scale : -1e30f;
        float s1 = (kg <= rg + 1) ? acc[t][1] * scale : -1e30f;
        float s2 = (kg <= rg + 2) ? acc[t][2] * scale : -1e30f;
        float s3 = (kg <= rg + 3) ? acc[t][3] * scale : -1e30f;
        acc[t][0] = s0; acc[t][1] = s1; acc[t][2] = s2; acc[t][3] = s3;
        Mx0 = fmaxf(Mx0, s0); Mx1 = fmaxf(Mx1, s1);
        Mx2 = fmaxf(Mx2, s2); Mx3 = fmaxf(Mx3, s3);
    }
#pragma unroll
    for (int m = 1; m < 16; m <<= 1) {
        Mx0 = fmaxf(Mx0, __shfl_xor(Mx0, m, 64));
        Mx1 = fmaxf(Mx1, __shfl_xor(Mx1, m, 64));
        Mx2 = fmaxf(Mx2, __shfl_xor(Mx2, m, 64));
        Mx3 = fmaxf(Mx3, __shfl_xor(Mx3, m, 64));
    }
    if (n16 == 0) {
        redM[kh2][rowDl + 0] = Mx0; redM[kh2][rowDl + 1] = Mx1;
        redM[kh2][rowDl + 2] = Mx2; redM[kh2][rowDl + 3] = Mx3;
    }
    __syncthreads();
    float Mg0 = fmaxf(redM[0][rowDl + 0], redM[1][rowDl + 0]);
    float Mg1 = fmaxf(redM[0][rowDl + 1], redM[1][rowDl + 1]);
    float Mg2 = fmaxf(redM[0][rowDl + 2], redM[1][rowDl + 2]);
    float Mg3 = fmaxf(redM[0][rowDl + 3], redM[1][rowDl + 3]);

    // ---- exp + row sum ----
    float S0 = 0.f, S1 = 0.f, S2 = 0.f, S3 = 0.f;
#pragma unroll
    for (int t = 0; t < 16; t++) {
        float e0 = __expf(acc[t][0] - Mg0);
        float e1 = __expf(acc[t][1] - Mg1);
        float e2 = __expf(acc[t][2] - Mg2);
        float e3 = __expf(acc[t][3] - Mg3);
        acc[t][0] = e0; acc[t][1] = e1; acc[t][2] = e2; acc[t][3] = e3;
        S0 += e0; S1 += e1; S2 += e2; S3 += e3;
    }
#pragma unroll
    for (int m = 1; m < 16; m <<= 1) {
        S0 += __shfl_xor(S0, m, 64); S1 += __shfl_xor(S1, m, 64);
        S2 += __shfl_xor(S2, m, 64); S3 += __shfl_xor(S3, m, 64);
    }
    if (n16 == 0) {
        redS[kh2][rowDl + 0] = S0; redS[kh2][rowDl + 1] = S1;
        redS[kh2][rowDl + 2] = S2; redS[kh2][rowDl + 3] = S3;
    }
    __syncthreads();
    const float i0 = Ac / (redS[0][rowDl + 0] + redS[1][rowDl + 0]);
    const float i1 = Ac / (redS[0][rowDl + 1] + redS[1][rowDl + 1]);
    const float i2 = Ac / (redS[0][rowDl + 2] + redS[1][rowDl + 2]);
    const float i3 = Ac / (redS[0][rowDl + 3] + redS[1][rowDl + 3]);

    // ---- store softmax part to P (bf16) ----
#pragma unroll
    for (int t = 0; t < 16; t++) {
        const int col = kbase + 16 * t + n16;
        Pl[(rowDl + 0) * PS + col] = bfbits(acc[t][0] * i0);
        Pl[(rowDl + 1) * PS + col] = bfbits(acc[t][1] * i1);
        Pl[(rowDl + 2) * PS + col] = bfbits(acc[t][2] * i2);
        Pl[(rowDl + 3) * PS + col] = bfbits(acc[t][3] * i3);
    }
    __syncthreads();

    // ---- blend with Ev + contiguous nontemporal prob write + P write-back.
    // One f32x4 per lane: each store instruction covers a contiguous 1 KB
    // across the wave.
#pragma unroll
    for (int it = 0; it < 16; it++) {
        const int idx = it * 256 + tid;           // 0..4095
        const int r = idx >> 7;                   // 0..31
        const int c0 = (idx & 127) * 4;           // 0..508
        short* pp = &Pl[r * PS + c0];
        short4v pv = *(short4v*)pp;
        const short4v ev = *(const short4v*)(Evb + ((size_t)(b * cS + q0 + r)) * cS + c0);
        f32x4 o;
#pragma unroll
        for (int j = 0; j < 4; j++) o[j] = bff(pv[j]) + bff(ev[j]);
        __builtin_nontemporal_store(o, (f32x4*)(prob + (bh * cS + q0 + r) * cS + c0));
#pragma unroll
        for (int j = 0; j < 4; j++) pv[j] = bfbits(o[j]);
        *(short4v*)pp = pv;
    }
    __syncthreads();

    // ---- PV: out^T(32x32) = V^T(32x512) @ P^T(512x32), 1 tile per wave ----
    const int dhT = w & 1, qT = w >> 1;
    const int dhA = 16 * dhT + n16;
    f32x4 oacc = (f32x4){0.f, 0.f, 0.f, 0.f};
    for (int k0 = 0; k0 < cS; k0 += 32) {
        const float* vp = vh + (bh * cS + k0 + quad * 8) * cDH + dhA;
        short8v av;
#pragma unroll
        for (int j = 0; j < 8; j++) av[j] = bfbits(vp[j * cDH]);
        short8v bv = *(short8v*)&Pl[(16 * qT + n16) * PS + k0 + quad * 8];
        oacc = __builtin_amdgcn_mfma_f32_16x16x32_bf16(av, bv, oacc, 0, 0, 0);
    }
    const int qg = q0 + 16 * qT + n16;
    const int dhD = 16 * dhT + quad * 4;
    float* op = out + ((size_t)b * cS + qg) * cD + h * cDH + dhD;
    __builtin_nontemporal_store(oacc, (f32x4*)op);
}

extern "C" void kernel_launch(void* const* d_in, const int* in_sizes, int n_in,
                              void* d_out, int out_size, void* d_ws, size_t ws_size,
                              hipStream_t stream) {
    const float* query = (const float*)d_in[0];
    const float* key   = (const float*)d_in[1];
    const float* value = (const float*)d_in[2];
    const float* rel   = (const float*)d_in[3];
    const float* tsp   = (const float*)d_in[4];
    const float* l1 = (const float*)d_in[6];
    const float* l2 = (const float*)d_in[7];
    const float* Wq = (const float*)d_in[8];
    const float* bq = (const float*)d_in[9];
    const float* Wk = (const float*)d_in[10];
    const float* bk = (const float*)d_in[11];
    const float* Wv = (const float*)d_in[12];
    const float* bv = (const float*)d_in[13];

    float* ws   = (float*)d_ws;
    short* Evb  = (short*)(ws + 3 * (size_t)cB * cS * cD);   // bf16, 8.4 MB
    float* out  = (float*)d_out;
    float* prob = out + (size_t)cB * cS * cD;

    proj_kernel<<<dim3(256, 3), 256, 0, stream>>>(query, key, value,
                                                  Wq, bq, Wk, bk, Wv, bv, ws);
    ev_kernel<<<dim3(2048), 256, 0, stream>>>(rel, tsp, l1, l2, Evb);
    attn2_kernel<<<dim3(16, 128), 256, 0, stream>>>(ws, Evb, l1, l2, out, prob);
}

// Round 5
// 400.467 us; speedup vs baseline: 1.0679x; 1.0046x over previous
//
#include <hip/hip_runtime.h>
#include <hip/hip_bf16.h>

static constexpr int cB  = 16;
static constexpr int cS  = 512;
static constexpr int cD  = 256;
static constexpr int cH  = 8;
static constexpr int cDH = 32;

typedef __attribute__((ext_vector_type(8))) short short8v;
typedef __attribute__((ext_vector_type(4))) short short4v;
typedef __attribute__((ext_vector_type(4))) float f32x4;

__device__ __forceinline__ short bfbits(float x) {
    __hip_bfloat16 h = __float2bfloat16(x);
    short s; __builtin_memcpy(&s, &h, 2); return s;
}
__device__ __forceinline__ float bff(short s) {
    __hip_bfloat16 h; __builtin_memcpy(&h, &s, 2); return __bfloat162float(h);
}

// ---------------------------------------------------------------------------
// Projection: C = X @ W^T + b via bf16 hi/lo MFMA (f32-grade accuracy).
// grid (8192/32, 3), block 256 (4 waves). No LDS. W fragments come from L2.
// z=0 (Q), z=1 (K): output f32 as (B,H,S,DH) into ws.
// z=2 (V): output bf16 TRANSPOSED as VT[b][h][dh][k] into the (otherwise
//          unused) f32 V slot — feeds PV with 16B vector loads instead of
//          128 scalar strided loads per wave. Values bit-identical to the
//          old in-PV __float2bfloat16 conversion.
// ---------------------------------------------------------------------------
__global__ __launch_bounds__(256) void proj_kernel(
    const float* __restrict__ q_in, const float* __restrict__ k_in,
    const float* __restrict__ v_in,
    const float* __restrict__ Wq, const float* __restrict__ bq,
    const float* __restrict__ Wk, const float* __restrict__ bk,
    const float* __restrict__ Wv, const float* __restrict__ bv,
    float* __restrict__ ws)
{
    const int z = blockIdx.y;
    const float* X    = (z == 0) ? q_in : (z == 1) ? k_in : v_in;
    const float* W    = (z == 0) ? Wq   : (z == 1) ? Wk   : Wv;
    const float* bias = (z == 0) ? bq   : (z == 1) ? bk   : bv;
    float* O = ws + (size_t)z * (cB * cS * cD);
    short* VTb = (short*)(ws + 2 * (size_t)cB * cS * cD);

    const int tid  = threadIdx.x;
    const int w    = tid >> 6;
    const int lane = tid & 63;
    const int n16  = lane & 15;
    const int quad = lane >> 4;

    const int i0 = blockIdx.x * 32 + 16 * (w & 1);   // wave's 16-row group
    const int j0 = 128 * (w >> 1);                   // wave's 128-col half

    // ---- A fragments: X rows, full K=256, bf16 hi/lo ----
    const float* xrow = X + (size_t)(i0 + n16) * cD + quad * 8;
    short8v a_hi[8], a_lo[8];
#pragma unroll
    for (int c = 0; c < 8; c++) {
        float xa[8];
        *(float4*)&xa[0] = *(const float4*)(xrow + c * 32);
        *(float4*)&xa[4] = *(const float4*)(xrow + c * 32 + 4);
#pragma unroll
        for (int j = 0; j < 8; j++) {
            short hb = bfbits(xa[j]);
            a_hi[c][j] = hb;
            a_lo[c][j] = bfbits(xa[j] - bff(hb));
        }
    }

    // ---- 8 col tiles of 16x16, K-chunks of 32 ----
#pragma unroll
    for (int t = 0; t < 8; t++) {
        const int jb = j0 + t * 16;
        const float* wrow = W + (size_t)(jb + n16) * cD + quad * 8;
        f32x4 acc = (f32x4){0.f, 0.f, 0.f, 0.f};
#pragma unroll
        for (int c = 0; c < 8; c++) {
            float wv_[8];
            *(float4*)&wv_[0] = *(const float4*)(wrow + c * 32);
            *(float4*)&wv_[4] = *(const float4*)(wrow + c * 32 + 4);
            short8v b_hi, b_lo;
#pragma unroll
            for (int j = 0; j < 8; j++) {
                short hb = bfbits(wv_[j]);
                b_hi[j] = hb;
                b_lo[j] = bfbits(wv_[j] - bff(hb));
            }
            acc = __builtin_amdgcn_mfma_f32_16x16x32_bf16(a_hi[c], b_hi, acc, 0, 0, 0);
            acc = __builtin_amdgcn_mfma_f32_16x16x32_bf16(a_hi[c], b_lo, acc, 0, 0, 0);
            acc = __builtin_amdgcn_mfma_f32_16x16x32_bf16(a_lo[c], b_hi, acc, 0, 0, 0);
        }
        // D: row = i0 + quad*4 + r, col = jb + n16
        const int jg = jb + n16;
        const float bv_ = bias[jg];
        const int h_ = jg >> 5, dh = jg & 31;
        if (z == 2) {
            // VT[b][h][dh][k=s] bf16
#pragma unroll
            for (int r = 0; r < 4; r++) {
                int gi = i0 + quad * 4 + r;
                int b_ = gi >> 9, s_ = gi & 511;
                VTb[(((size_t)(b_ * cH + h_)) * cDH + dh) * cS + s_] =
                    bfbits(acc[r] + bv_);
            }
        } else {
#pragma unroll
            for (int r = 0; r < 4; r++) {
                int gi = i0 + quad * 4 + r;
                int b_ = gi >> 9, s_ = gi & 511;
                O[(((size_t)(b_ * cH + h_)) * cS + s_) * cDH + dh] = acc[r] + bv_;
            }
        }
    }
}

// ---------------------------------------------------------------------------
// Ev kernel: Ev[b][q][k] = Bc*time_attn + Cc*rel_attn  (head-independent),
// stored bf16. One wave per (b,q) row. Triangular predicated loads.
// ---------------------------------------------------------------------------
__global__ __launch_bounds__(256) void ev_kernel(
    const float* __restrict__ rel, const float* __restrict__ ts,
    const float* __restrict__ l1p, const float* __restrict__ l2p,
    short* __restrict__ Evb)
{
    const int w = threadIdx.x >> 6, lane = threadIdx.x & 63;
    const int row = blockIdx.x * 4 + w;          // b*512 + q
    const int q = row & 511;
    const float* tr = ts  + (size_t)row * cS;
    const float* rr = rel + (size_t)row * cS;
    const float l1 = l1p[0], l2 = l2p[0];
    const float Bc = (1.f - l1) * l2;
    const float Cc = l1;

    float tv[8], rv[8];
    float tmax = -1e30f, rmax = -1e30f;
#pragma unroll
    for (int j = 0; j < 8; j++) {
        int k = lane + 64 * j;
        float tl_ = (k <= q) ? tr[k] : 0.f;
        float r   = (k >  q) ? rr[k] : 0.f;
        tv[j] = (k <= q) ? __expf(-fabsf(tl_)) : -1e30f;
        rv[j] = (k > q && r != 0.f) ? r : -10000.f;
        tmax = fmaxf(tmax, tv[j]);
        rmax = fmaxf(rmax, rv[j]);
    }
#pragma unroll
    for (int m = 1; m < 64; m <<= 1) {
        tmax = fmaxf(tmax, __shfl_xor(tmax, m, 64));
        rmax = fmaxf(rmax, __shfl_xor(rmax, m, 64));
    }
    float te[8], re[8];
    float tsum = 0.f, rsum = 0.f;
#pragma unroll
    for (int j = 0; j < 8; j++) {
        te[j] = (tv[j] > -1e29f) ? __expf(tv[j] - tmax) : 0.f;
        re[j] = __expf(rv[j] - rmax);
        tsum += te[j]; rsum += re[j];
    }
#pragma unroll
    for (int m = 1; m < 64; m <<= 1) {
        tsum += __shfl_xor(tsum, m, 64);
        rsum += __shfl_xor(rsum, m, 64);
    }
    const float ti = Bc / tsum, ri = Cc / rsum;
#pragma unroll
    for (int j = 0; j < 8; j++) {
        int k = lane + 64 * j;
        Evb[(size_t)row * cS + k] = bfbits(te[j] * ti + re[j] * ri);
    }
}

// ---------------------------------------------------------------------------
// Attention v5: XCD-aware block remap; PV reads precomputed bf16 V^T with
// one 16B vector load per k0-tile (replaces 8 scalar 128B-strided loads +
// 8 converts per iter — the kernel's dominant latency chain).
// ---------------------------------------------------------------------------
__global__ __launch_bounds__(256, 4) void attn2_kernel(
    const float* __restrict__ ws, const short* __restrict__ Evb,
    const float* __restrict__ l1p, const float* __restrict__ l2p,
    float* __restrict__ out, float* __restrict__ prob)
{
    constexpr int PS = 536;                       // P row stride (bf16 elems)
    __shared__ short Pl[32 * PS];                 // 33.5 KB
    __shared__ float redM[2][32];
    __shared__ float redS[2][32];

    const int tid  = threadIdx.x;
    const int w    = tid >> 6;
    const int lane = tid & 63;
    const int n16  = lane & 15;
    const int quad = lane >> 4;

    // ---- XCD-aware remap: all 128 blocks of batch b land on XCD b%8 so
    // K/VT (fetched once) and Ev stay L2-resident per XCD.
    const int flat = blockIdx.y * gridDim.x + blockIdx.x;   // 0..2047
    const int xcd  = flat & 7;
    const int slot = flat >> 3;                   // 0..255
    const int b  = xcd + 8 * (slot >> 7);         // 0..15
    const int h  = (slot >> 4) & 7;               // 0..7
    const int qt = slot & 15;                     // 0..15
    const size_t bh = (size_t)b * cH + h;
    const int q0 = qt * 32;

    const float* qh = ws;
    const float* kh = ws + (size_t)cB * cS * cD;
    const short* VTb = (const short*)(ws + 2 * (size_t)cB * cS * cD);

    const float l1 = l1p[0], l2 = l2p[0];
    const float Ac = (1.f - l1) * (1.f - l2);

    const int qhH = w & 1;                        // which 16 q rows
    const int kh2 = w >> 1;                       // which 256 keys
    const int kbase = 256 * kh2;

    // ---- A fragment: Q rows (hi/lo bf16 split) ----
    const int rowA = q0 + 16 * qhH + n16;
    const float* qrow = qh + (bh * cS + rowA) * cDH + quad * 8;
    float qa[8];
    *(float4*)&qa[0] = *(const float4*)qrow;
    *(float4*)&qa[4] = *(const float4*)(qrow + 4);
    short8v a_hi, a_lo;
#pragma unroll
    for (int j = 0; j < 8; j++) {
        short hbits = bfbits(qa[j]);
        a_hi[j] = hbits;
        a_lo[j] = bfbits(qa[j] - bff(hbits));
    }

    // ---- QK^T MFMA over this wave's 16 key tiles ----
    f32x4 acc[16];
#pragma unroll
    for (int t = 0; t < 16; t++) acc[t] = (f32x4){0.f, 0.f, 0.f, 0.f};

    const int tl = (kbase <= q0 + 31) ? min(15, (q0 + 31 - kbase) >> 4) : -1;
    for (int t = 0; t <= tl; t++) {
        const float* krow = kh + (bh * cS + kbase + 16 * t + n16) * cDH + quad * 8;
        float kb[8];
        *(float4*)&kb[0] = *(const float4*)krow;
        *(float4*)&kb[4] = *(const float4*)(krow + 4);
        short8v b_hi, b_lo;
#pragma unroll
        for (int j = 0; j < 8; j++) {
            short hbits = bfbits(kb[j]);
            b_hi[j] = hbits;
            b_lo[j] = bfbits(kb[j] - bff(hbits));
        }
        acc[t] = __builtin_amdgcn_mfma_f32_16x16x32_bf16(a_hi, b_hi, acc[t], 0, 0, 0);
        acc[t] = __builtin_amdgcn_mfma_f32_16x16x32_bf16(a_hi, b_lo, acc[t], 0, 0, 0);
        acc[t] = __builtin_amdgcn_mfma_f32_16x16x32_bf16(a_lo, b_hi, acc[t], 0, 0, 0);
    }

    // ---- mask + scale + row max (rows rowD = q0+16*qhH+quad*4+r) ----
    const float scale = 0.17677669529663687f;
    const int rowDl = 16 * qhH + quad * 4;        // local row base (0..28)
    float Mx0 = -1e30f, Mx1 = -1e30f, Mx2 = -1e30f, Mx3 = -1e30f;
#pragma unroll
    for (int t = 0; t < 16; t++) {
        const int kg = kbase + 16 * t + n16;
        const int rg = q0 + rowDl;
        float s0 = (kg <= rg + 0) ? acc[t][0] * scale : -1e30f;
        float s1 = (kg <= rg + 1) ? acc[t][1] * scale : -1e30f;
        float s2 = (kg <= rg + 2) ? acc[t][2] * scale : -1e30f;
        float s3 = (kg <= rg + 3) ? acc[t][3] * scale : -1e30f;
        acc[t][0] = s0; acc[t][1] = s1; acc[t][2] = s2; acc[t][3] = s3;
        Mx0 = fmaxf(Mx0, s0); Mx1 = fmaxf(Mx1, s1);
        Mx2 = fmaxf(Mx2, s2); Mx3 = fmaxf(Mx3, s3);
    }
#pragma unroll
    for (int m = 1; m < 16; m <<= 1) {
        Mx0 = fmaxf(Mx0, __shfl_xor(Mx0, m, 64));
        Mx1 = fmaxf(Mx1, __shfl_xor(Mx1, m, 64));
        Mx2 = fmaxf(Mx2, __shfl_xor(Mx2, m, 64));
        Mx3 = fmaxf(Mx3, __shfl_xor(Mx3, m, 64));
    }
    if (n16 == 0) {
        redM[kh2][rowDl + 0] = Mx0; redM[kh2][rowDl + 1] = Mx1;
        redM[kh2][rowDl + 2] = Mx2; redM[kh2][rowDl + 3] = Mx3;
    }
    __syncthreads();
    float Mg0 = fmaxf(redM[0][rowDl + 0], redM[1][rowDl + 0]);
    float Mg1 = fmaxf(redM[0][rowDl + 1], redM[1][rowDl + 1]);
    float Mg2 = fmaxf(redM[0][rowDl + 2], redM[1][rowDl + 2]);
    float Mg3 = fmaxf(redM[0][rowDl + 3], redM[1][rowDl + 3]);

    // ---- exp + row sum ----
    float S0 = 0.f, S1 = 0.f, S2 = 0.f, S3 = 0.f;
#pragma unroll
    for (int t = 0; t < 16; t++) {
        float e0 = __expf(acc[t][0] - Mg0);
        float e1 = __expf(acc[t][1] - Mg1);
        float e2 = __expf(acc[t][2] - Mg2);
        float e3 = __expf(acc[t][3] - Mg3);
        acc[t][0] = e0; acc[t][1] = e1; acc[t][2] = e2; acc[t][3] = e3;
        S0 += e0; S1 += e1; S2 += e2; S3 += e3;
    }
#pragma unroll
    for (int m = 1; m < 16; m <<= 1) {
        S0 += __shfl_xor(S0, m, 64); S1 += __shfl_xor(S1, m, 64);
        S2 += __shfl_xor(S2, m, 64); S3 += __shfl_xor(S3, m, 64);
    }
    if (n16 == 0) {
        redS[kh2][rowDl + 0] = S0; redS[kh2][rowDl + 1] = S1;
        redS[kh2][rowDl + 2] = S2; redS[kh2][rowDl + 3] = S3;
    }
    __syncthreads();
    const float i0 = Ac / (redS[0][rowDl + 0] + redS[1][rowDl + 0]);
    const float i1 = Ac / (redS[0][rowDl + 1] + redS[1][rowDl + 1]);
    const float i2 = Ac / (redS[0][rowDl + 2] + redS[1][rowDl + 2]);
    const float i3 = Ac / (redS[0][rowDl + 3] + redS[1][rowDl + 3]);

    // ---- store softmax part to P (bf16) ----
#pragma unroll
    for (int t = 0; t < 16; t++) {
        const int col = kbase + 16 * t + n16;
        Pl[(rowDl + 0) * PS + col] = bfbits(acc[t][0] * i0);
        Pl[(rowDl + 1) * PS + col] = bfbits(acc[t][1] * i1);
        Pl[(rowDl + 2) * PS + col] = bfbits(acc[t][2] * i2);
        Pl[(rowDl + 3) * PS + col] = bfbits(acc[t][3] * i3);
    }
    __syncthreads();

    // ---- blend with Ev + contiguous nontemporal prob write + P write-back ----
#pragma unroll
    for (int it = 0; it < 16; it++) {
        const int idx = it * 256 + tid;           // 0..4095
        const int r = idx >> 7;                   // 0..31
        const int c0 = (idx & 127) * 4;           // 0..508
        short* pp = &Pl[r * PS + c0];
        short4v pv = *(short4v*)pp;
        const short4v ev = *(const short4v*)(Evb + ((size_t)(b * cS + q0 + r)) * cS + c0);
        f32x4 o;
#pragma unroll
        for (int j = 0; j < 4; j++) o[j] = bff(pv[j]) + bff(ev[j]);
        __builtin_nontemporal_store(o, (f32x4*)(prob + (bh * cS + q0 + r) * cS + c0));
#pragma unroll
        for (int j = 0; j < 4; j++) pv[j] = bfbits(o[j]);
        *(short4v*)pp = pv;
    }
    __syncthreads();

    // ---- PV: out^T(32x32) = V^T(32x512) @ P^T(512x32), 1 tile per wave.
    // A-fragment from precomputed VT[bh][dh][k]: one short8v (16B) load per
    // k0 (16 rows x 64B coalesced, L2-resident), no converts.
    const int dhT = w & 1, qT = w >> 1;
    const int dhA = 16 * dhT + n16;
    const short* vtrow = VTb + (bh * cDH + dhA) * cS;
    f32x4 oacc = (f32x4){0.f, 0.f, 0.f, 0.f};
#pragma unroll
    for (int k0 = 0; k0 < cS; k0 += 32) {
        short8v av = *(const short8v*)(vtrow + k0 + quad * 8);
        short8v bv = *(short8v*)&Pl[(16 * qT + n16) * PS + k0 + quad * 8];
        oacc = __builtin_amdgcn_mfma_f32_16x16x32_bf16(av, bv, oacc, 0, 0, 0);
    }
    const int qg = q0 + 16 * qT + n16;
    const int dhD = 16 * dhT + quad * 4;
    float* op = out + ((size_t)b * cS + qg) * cD + h * cDH + dhD;
    __builtin_nontemporal_store(oacc, (f32x4*)op);
}

extern "C" void kernel_launch(void* const* d_in, const int* in_sizes, int n_in,
                              void* d_out, int out_size, void* d_ws, size_t ws_size,
                              hipStream_t stream) {
    const float* query = (const float*)d_in[0];
    const float* key   = (const float*)d_in[1];
    const float* value = (const float*)d_in[2];
    const float* rel   = (const float*)d_in[3];
    const float* tsp   = (const float*)d_in[4];
    const float* l1 = (const float*)d_in[6];
    const float* l2 = (const float*)d_in[7];
    const float* Wq = (const float*)d_in[8];
    const float* bq = (const float*)d_in[9];
    const float* Wk = (const float*)d_in[10];
    const float* bk = (const float*)d_in[11];
    const float* Wv = (const float*)d_in[12];
    const float* bv = (const float*)d_in[13];

    float* ws   = (float*)d_ws;
    short* Evb  = (short*)(ws + 3 * (size_t)cB * cS * cD);   // bf16, 8.4 MB
    float* out  = (float*)d_out;
    float* prob = out + (size_t)cB * cS * cD;

    proj_kernel<<<dim3(256, 3), 256, 0, stream>>>(query, key, value,
                                                  Wq, bq, Wk, bk, Wv, bv, ws);
    ev_kernel<<<dim3(2048), 256, 0, stream>>>(rel, tsp, l1, l2, Evb);
    attn2_kernel<<<dim3(16, 128), 256, 0, stream>>>(ws, Evb, l1, l2, out, prob);
}